// Round 1
// 124.073 us; speedup vs baseline: 1.0090x; 1.0090x over previous
//
#include <hip/hip_runtime.h>

// CharGRU2: 2-layer GRU (reset_after=true) + dense + softmax, fp32.
// B=2048, T=128, V=256, H=20, L=15.
//
// Round 13 = R12 (cross-layer pipeline, DPP gate hops, LDS h broadcast,
// pk_fma dots, 2 waves/SIMD) + stall-decorrelation + pipeline rotation:
//
//  1. WAVE STAGGER: the 2 waves/SIMD come from the 2 blocks resident per CU;
//     both run the identical instruction stream in lockstep, so their
//     exp/rcp dependency chains and lgkmcnt waits stall SIMULTANEOUSLY
//     (VALUBusy 62%, everything else ~0). Half the blocks sleep ~384 cyc
//     (~1/2 iteration) at entry so the co-resident pair anti-phases:
//     one wave's dot/gate issue fills the other's trans-latency stalls.
//     Parity = bit3 XOR bit8 of blockIdx covers both plausible CU pairings
//     ((i,i+8) and (i,i+256) under XCD round-robin).
//  2. DOTS ROTATED INTO THE LOOP TAIL: rec0/xw1/rec1 for iteration i+1 are
//     computed at the bottom of iteration i from the freshly-prefetched
//     c0/c1 register quads and carried as scalars across the backedge.
//     The loop top now enters the L0 gate chain IMMEDIATELY (previously
//     ~60 cyc of dot issue+chain sat on the critical path first). The last
//     tail (i=127) naturally produces the epilogue's xw1/rec1.
//  3. Horizontal reductions: one v_pk_add_f32 + one scalar add per dot
//     (was 3 scalar adds).
//
// Layout recap: lane 16r+3u+p owns gate column p*20+(5r+u) (p=0:z 1:r 2:h~);
// gate hops are two chained v_mov_dpp row_shr:1 (never cross a 16-lane row);
// lane 16r+15 idles (dups pos 14, excluded from LDS writes).

#define BB 2048
#define TT 128
#define HH 20
#define LL 15
#define H3 60

typedef float v2f __attribute__((ext_vector_type(2)));

__device__ __forceinline__ float bclane(float v, int k) {
    return __int_as_float(__builtin_amdgcn_readlane(__float_as_int(v), k));
}
__device__ __forceinline__ float dpp_rshr1(float v) {
    // v_mov_b32_dpp row_shr:1 — lane i <- lane i-1 within its 16-lane row
    return __int_as_float(__builtin_amdgcn_update_dpp(
        0, __float_as_int(v), 0x111, 0xF, 0xF, true));
}
__device__ __forceinline__ float fast_rcp(float x) { return __builtin_amdgcn_rcpf(x); }
__device__ __forceinline__ float sigm(float x) { return fast_rcp(1.f + __expf(-x)); }
__device__ __forceinline__ float tanh_f(float x) { return 1.f - 2.f * fast_rcp(1.f + __expf(2.f * x)); }
#define PIN(v) asm volatile("" : "+v"(v))
#define LDSFENCE() asm volatile("" ::: "memory")

extern "C" __global__ __launch_bounds__(256)
__attribute__((amdgpu_waves_per_eu(2, 2)))
void gru2_kernel(const int* __restrict__ x, const float* __restrict__ W0,
                 const float* __restrict__ U0, const float* __restrict__ b0i,
                 const float* __restrict__ b0r, const float* __restrict__ W1,
                 const float* __restrict__ U1, const float* __restrict__ b1i,
                 const float* __restrict__ b1r, const float* __restrict__ Wd,
                 const float* __restrict__ bd, float* __restrict__ out)
{
    // ---- stall decorrelation: anti-phase the co-resident block pair ----
    if (((blockIdx.x >> 3) ^ (blockIdx.x >> 8)) & 1)
        __builtin_amdgcn_s_sleep(6);                     // ~384 cyc ≈ 1/2 iter

    const int lane = threadIdx.x & 63;
    const int w = threadIdx.x >> 6;
    const int b = blockIdx.x * 4 + w;                    // batch = wave id
    const int row = lane >> 4;                           // DPP row 0..3
    const int pos = lane & 15;                           // pos in row
    const int pc  = (pos < 15) ? pos : 14;               // lane 16r+15 dups pos 14
    const int u   = pc / 3;                              // unit-in-row 0..4
    const int p3  = pc % 3;                              // 0:z 1:r 2:h~
    const int j   = row * 5 + u;                         // unit 0..19
    const bool home = (pos < 15) && (p3 == 2);           // 20 h-home lanes
    const int col = p3 * 20 + j;                         // owned gate column

    // per-wave LDS staging of h0/h1 (wave-uniform broadcast reads)
    __shared__ __align__(16) float hbuf[4][2][24];
    float* h0buf = &hbuf[w][0][0];
    float* h1buf = &hbuf[w][1][0];
    const float4* h0q = (const float4*)h0buf;
    const float4* h1q = (const float4*)h1buf;
    if (home) { h0buf[j] = 0.f; h1buf[j] = 0.f; }
    LDSFENCE();

    // ---- weight columns (k-pair packed) into VGPRs, pinned ----
    v2f u0p[10], w1p[10], u1p[10];
#pragma unroll
    for (int q = 0; q < 10; ++q) {
        const int k0 = (2 * q) * H3, k1 = (2 * q + 1) * H3;
        u0p[q] = v2f{U0[k0 + col], U0[k1 + col]};
        w1p[q] = v2f{W1[k0 + col], W1[k1 + col]};
        u1p[q] = v2f{U1[k0 + col], U1[k1 + col]};
    }
#pragma unroll
    for (int q = 0; q < 10; ++q) { PIN(u0p[q]); PIN(w1p[q]); PIN(u1p[q]); }
    float bi0 = b0i[col], br0 = b0r[col], bi1 = b1i[col], br1 = b1r[col];
    PIN(bi0); PIN(br0); PIN(bi1); PIN(br1);

    // ---- tokens ----
    const int* xrow = x + b * TT;
    const int tokA = xrow[lane];
    const int tokB = xrow[64 + lane];

    float h0 = 0.f, h1 = 0.f;                            // home lanes hold state

    // ---- W0 pipeline: row t ready, row t+1 raw, token t+2 staged ----
    const int tok0 = __builtin_amdgcn_readlane(tokA, 0);
    const int tok1 = __builtin_amdgcn_readlane(tokA, 1);
    int tokn2 = __builtin_amdgcn_readlane(tokA, 2);
    float xw_cur = W0[tok0 * H3 + col] + bi0;
    float xw_nxt = W0[tok1 * H3 + col];

    float4 c0[5], c1[5];                                 // register-staged h quads
    float rec0, xw1, rec1;                               // carried dot results

    // tail dot block: consumes c0 (=h0_t), c1 (=h1_{t-1}) -> scalars for next iter
#define DOTS()                                                                \
    {                                                                         \
        v2f a0a = v2f{br0, 0.f}, a0b = v2f{0.f, 0.f};                         \
        v2f a1a = v2f{bi1, 0.f}, a1b = v2f{0.f, 0.f};                         \
        v2f a2a = v2f{br1, 0.f}, a2b = v2f{0.f, 0.f};                         \
        _Pragma("unroll")                                                     \
        for (int q = 0; q < 5; ++q) {                                         \
            const v2f hA = v2f{c0[q].x, c0[q].y}, hB = v2f{c0[q].z, c0[q].w}; \
            a0a = __builtin_elementwise_fma(hA, u0p[2 * q], a0a);             \
            a0b = __builtin_elementwise_fma(hB, u0p[2 * q + 1], a0b);         \
            a1a = __builtin_elementwise_fma(hA, w1p[2 * q], a1a);             \
            a1b = __builtin_elementwise_fma(hB, w1p[2 * q + 1], a1b);         \
        }                                                                     \
        _Pragma("unroll")                                                     \
        for (int q = 0; q < 5; ++q) {                                         \
            const v2f gA = v2f{c1[q].x, c1[q].y}, gB = v2f{c1[q].z, c1[q].w}; \
            a2a = __builtin_elementwise_fma(gA, u1p[2 * q], a2a);             \
            a2b = __builtin_elementwise_fma(gB, u1p[2 * q + 1], a2b);         \
        }                                                                     \
        { const v2f t = a0a + a0b; rec0 = t.x + t.y; }                        \
        { const v2f t = a1a + a1b; xw1  = t.x + t.y; }                        \
        { const v2f t = a2a + a2b; rec1 = t.x + t.y; }                        \
    }

    // ---- prologue: L0 for t=0 (h0_{-1}=0 -> rec0 = br0), then dots for i=1 ----
    {
        const float pf = W0[tokn2 * H3 + col];
        const int tokn3 = __builtin_amdgcn_readlane(tokA, 3);
        const float sg0 = sigm(xw_cur + br0);            // z on p=0, r on p=1
        const float rv0 = dpp_rshr1(sg0);                // home <- r_j
        const float zv0 = dpp_rshr1(rv0);                // home <- z_j
        const float hh0 = tanh_f(xw_cur + rv0 * br0);
        h0 = fmaf(zv0, h0 - hh0, hh0);
        if (home) h0buf[j] = h0;
        LDSFENCE();
#pragma unroll
        for (int q = 0; q < 5; ++q) { c0[q] = h0q[q]; c1[q] = h1q[q]; }
        xw_cur = xw_nxt + bi0; xw_nxt = pf; tokn2 = tokn3;
        DOTS();                                          // rec0/xw1/rec1 for i=1
    }

    // ---- main loop: i = 1..127, L0(t=i) + L1(t=i-1); gates first, dots in tail
#pragma unroll 2
    for (int i = 1; i < TT; ++i) {
        const int t3 = (i + 3 < TT) ? (i + 3) : (TT - 1);
        const float pf = W0[tokn2 * H3 + col];
        const int tokn3 = __builtin_amdgcn_readlane(t3 < 64 ? tokA : tokB, t3 & 63);

        // ---- L0 gates (t=i): rec0 carried, chain starts immediately ----
        const float sg0 = sigm(xw_cur + rec0);
        const float rv0 = dpp_rshr1(sg0);
        const float zv0 = dpp_rshr1(rv0);
        const float hh0 = tanh_f(xw_cur + rv0 * rec0);
        h0 = fmaf(zv0, h0 - hh0, hh0);
        if (home) h0buf[j] = h0;
        LDSFENCE();
        // prefetch h0 quads — latency hides behind L1 gates
#pragma unroll
        for (int q = 0; q < 5; ++q) c0[q] = h0q[q];

        // ---- L1 gates (t=i-1): independent of L0 above ----
        const float sg1 = sigm(xw1 + rec1);
        const float rv1 = dpp_rshr1(sg1);
        const float zv1 = dpp_rshr1(rv1);
        const float hh1 = tanh_f(xw1 + rv1 * rec1);
        h1 = fmaf(zv1, h1 - hh1, hh1);
        if (home) h1buf[j] = h1;
        LDSFENCE();
        // prefetch h1 quads — hides behind rotation + tail dots
#pragma unroll
        for (int q = 0; q < 5; ++q) c1[q] = h1q[q];

        // rotate W0 pipeline
        xw_cur = xw_nxt + bi0; xw_nxt = pf; tokn2 = tokn3;

        // ---- tail dots for i+1 (at i=127: xw1/rec1 feed the epilogue;
        //      rec0 is one wasted dot) ----
        DOTS();
    }

    // ---- epilogue: L1 for t=127 (xw1/rec1 from the last tail) ----
    {
        const float sg1 = sigm(xw1 + rec1);
        const float rv1 = dpp_rshr1(sg1);
        const float zv1 = dpp_rshr1(rv1);
        const float hh1 = tanh_f(xw1 + rv1 * rec1);
        h1 = fmaf(zv1, h1 - hh1, hh1);
        if (home) h1buf[j] = h1;                         // final h1
        LDSFENCE();
    }

    // ---- dense (h1 @ Wd + bd) + softmax, lanes 0..14 ----
    const int l = lane < LL ? lane : LL - 1;
    float acc = bd[l];
#pragma unroll
    for (int k = 0; k < HH; ++k)
        acc = fmaf(h1buf[k], Wd[k * LL + l], acc);       // LDS broadcast reads

    float m = acc;
#pragma unroll
    for (int i = 0; i < LL; ++i) m = fmaxf(m, bclane(acc, i));
    const float e = __expf(acc - m);
    float s = 0.f;
#pragma unroll
    for (int i = 0; i < LL; ++i) s += bclane(e, i);
    const float pr = e * fast_rcp(s);

    if (lane < LL) out[b * LL + lane] = pr;
}

extern "C" void kernel_launch(void* const* d_in, const int* in_sizes, int n_in,
                              void* d_out, int out_size, void* d_ws, size_t ws_size,
                              hipStream_t stream) {
    const int*   x   = (const int*)  d_in[0];
    const float* W0  = (const float*)d_in[1];
    const float* U0  = (const float*)d_in[2];
    const float* b0i = (const float*)d_in[3];
    const float* b0r = (const float*)d_in[4];
    const float* W1  = (const float*)d_in[5];
    const float* U1  = (const float*)d_in[6];
    const float* b1i = (const float*)d_in[7];
    const float* b1r = (const float*)d_in[8];
    const float* Wd  = (const float*)d_in[9];
    const float* bd  = (const float*)d_in[10];
    // d_in[11] = drop_rate (identity), unused
    float* out = (float*)d_out;

    // 1 batch/wave, 4 waves/block -> 512 blocks = 2 blocks/CU = 2 waves/SIMD.
    dim3 grid(BB / 4), block(256);
    hipLaunchKernelGGL(gru2_kernel, grid, block, 0, stream,
                       x, W0, U0, b0i, b0r, W1, U1, b1i, b1r, Wd, bd, out);
}